// Round 1
// baseline (3612.796 us; speedup 1.0000x reference)
//
#include <hip/hip_runtime.h>
#include <hip/hip_bf16.h>

// H2Conv: Xh = lorentz_linear(X W^T + b); Xve = Xh[vertex]-emb[ty];
// Xe = segsum(Xve, edges); Xv = segsum(Xe[edges], vertex); out = eps*Xv + Xh
//
// Constants from reference: N=100000, E=20000, NNZ=1e6, IN_CH=D=128, K_CURV=1
#define E_SEGS 20000

// ---------------- Kernel 1: fused GEMM + lorentz epilogue -------------------
// Block = 256 threads, 64 rows/block. LDS: W transposed [128][132] (67.5KB) +
// X tile transposed [128][64] (32KB) -> ~100KB, 1 block/CU, 4 waves.
// Thread tile: 4 rows x 8 cols -> 3 ds_read_b128 per 32 v_fmac (FMA-bound).
__global__ __launch_bounds__(256) void lorentz_gemm_kernel(
    const float* __restrict__ X, const float* __restrict__ W,
    const float* __restrict__ bias, const float* __restrict__ scale_log,
    float* __restrict__ Xh, float* __restrict__ out, int N)
{
    __shared__ float Wt[128][132];   // Wt[k][d], pad 132 keeps float4 align
    __shared__ float Xs[128][64];    // Xs[k][r]
    const int t = threadIdx.x;

    // Load W (128x128) transposed into LDS. 16 float4 per thread, coalesced.
    #pragma unroll
    for (int i = 0; i < 16; ++i) {
        int f4 = t + i * 256;            // float4 index 0..4095
        int d  = f4 >> 5;                // row of W
        int k0 = (f4 & 31) << 2;         // col of W (k)
        float4 w = ((const float4*)W)[f4];
        Wt[k0+0][d] = w.x; Wt[k0+1][d] = w.y;
        Wt[k0+2][d] = w.z; Wt[k0+3][d] = w.w;
    }
    // Load X tile (64 rows) transposed into LDS. 8 float4 per thread.
    const int row0 = blockIdx.x * 64;
    #pragma unroll
    for (int i = 0; i < 8; ++i) {
        int f4 = t + i * 256;            // 0..2047
        int r  = f4 >> 5;
        int k0 = (f4 & 31) << 2;
        int gr = row0 + r;
        float4 x = make_float4(0.f, 0.f, 0.f, 0.f);
        if (gr < N) x = ((const float4*)X)[(size_t)gr * 32 + (f4 & 31)];
        Xs[k0+0][r] = x.x; Xs[k0+1][r] = x.y;
        Xs[k0+2][r] = x.z; Xs[k0+3][r] = x.w;
    }
    __syncthreads();

    const int rg = t >> 4;               // 0..15 -> local rows rg*4..+3
    const int cg = t & 15;               // 0..15 -> cols cg*8..+7
    const int cb = cg << 3;

    float acc[4][8];
    #pragma unroll
    for (int r = 0; r < 4; ++r)
        #pragma unroll
        for (int j = 0; j < 8; ++j) acc[r][j] = 0.f;

    #pragma unroll 4
    for (int k = 0; k < 128; ++k) {
        float4 xr = *(const float4*)&Xs[k][rg << 2];
        float4 w0 = *(const float4*)&Wt[k][cb];
        float4 w1 = *(const float4*)&Wt[k][cb + 4];
        #pragma unroll
        for (int r = 0; r < 4; ++r) {
            float xv = (&xr.x)[r];
            acc[r][0] += xv * w0.x; acc[r][1] += xv * w0.y;
            acc[r][2] += xv * w0.z; acc[r][3] += xv * w0.w;
            acc[r][4] += xv * w1.x; acc[r][5] += xv * w1.y;
            acc[r][6] += xv * w1.z; acc[r][7] += xv * w1.w;
        }
    }

    // bias
    float4 b0 = ((const float4*)bias)[cg * 2];
    float4 b1 = ((const float4*)bias)[cg * 2 + 1];
    #pragma unroll
    for (int r = 0; r < 4; ++r) {
        acc[r][0] += b0.x; acc[r][1] += b0.y; acc[r][2] += b0.z; acc[r][3] += b0.w;
        acc[r][4] += b1.x; acc[r][5] += b1.y; acc[r][6] += b1.z; acc[r][7] += b1.w;
    }

    const float es = expf(scale_log[0]);

    // Lorentz epilogue: per row, sq = sum_{c>=1} y_c^2 (16-lane reduce),
    // time = sigmoid(y0)*es + 1.1, scale = (time^2-1)/(sq+1e-8)
    #pragma unroll
    for (int r = 0; r < 4; ++r) {
        float sq = 0.f;
        #pragma unroll
        for (int j = 0; j < 8; ++j) sq += acc[r][j] * acc[r][j];
        if (cg == 0) sq -= acc[r][0] * acc[r][0];   // exclude time channel
        #pragma unroll
        for (int m = 1; m < 16; m <<= 1) sq += __shfl_xor(sq, m, 16);
        float y0   = __shfl(acc[r][0], 0, 16);
        float time = es / (1.f + expf(-y0)) + 1.1f;
        float ss   = sqrtf((time * time - 1.f) / (sq + 1e-8f));
        float4 o0, o1;
        o0.x = (cg == 0) ? time : acc[r][0] * ss;
        o0.y = acc[r][1] * ss; o0.z = acc[r][2] * ss; o0.w = acc[r][3] * ss;
        o1.x = acc[r][4] * ss; o1.y = acc[r][5] * ss;
        o1.z = acc[r][6] * ss; o1.w = acc[r][7] * ss;
        int grow = row0 + (rg << 2) + r;
        if (grow < N) {
            float4* ph = (float4*)(Xh + (size_t)grow * 128 + cb);
            ph[0] = o0; ph[1] = o1;
            float4* po = (float4*)(out + (size_t)grow * 128 + cb);
            po[0] = o0; po[1] = o1;   // out starts as Xh (final: += eps*Xv)
        }
    }
}

// ---------------- Kernel 2: edge scatter: Xe += Xh[vertex] - emb[ty] --------
// 32 threads per edge, float4 per thread (128 floats/row).
__global__ __launch_bounds__(256) void edge_scatter_kernel(
    const float* __restrict__ Xh, const float* __restrict__ emb,
    const int* __restrict__ vertex, const int* __restrict__ edges,
    const int* __restrict__ types, float* __restrict__ Xe, int nnz)
{
    int gid = blockIdx.x * 256 + threadIdx.x;
    int e   = gid >> 5;
    if (e >= nnz) return;
    int c4 = gid & 31;
    int v  = vertex[e];
    int s  = edges[e];
    int ty = types[e];
    float4 x = ((const float4*)Xh)[(size_t)v * 32 + c4];
    float4 m = ((const float4*)emb)[ty * 32 + c4];
    float* dst = Xe + (size_t)s * 128 + (c4 << 2);
    atomicAdd(dst + 0, x.x - m.x);
    atomicAdd(dst + 1, x.y - m.y);
    atomicAdd(dst + 2, x.z - m.z);
    atomicAdd(dst + 3, x.w - m.w);
}

// ---------------- Kernel 3: vertex scatter: out += eps * Xe[edges] ----------
__global__ __launch_bounds__(256) void vertex_scatter_kernel(
    const float* __restrict__ Xe, const int* __restrict__ vertex,
    const int* __restrict__ edges, const float* __restrict__ eps,
    float* __restrict__ out, int nnz)
{
    int gid = blockIdx.x * 256 + threadIdx.x;
    int e   = gid >> 5;
    if (e >= nnz) return;
    int c4 = gid & 31;
    int s  = edges[e];
    int v  = vertex[e];
    float ep = eps[0];
    float4 x = ((const float4*)Xe)[(size_t)s * 32 + c4];
    float* dst = out + (size_t)v * 128 + (c4 << 2);
    atomicAdd(dst + 0, ep * x.x);
    atomicAdd(dst + 1, ep * x.y);
    atomicAdd(dst + 2, ep * x.z);
    atomicAdd(dst + 3, ep * x.w);
}

extern "C" void kernel_launch(void* const* d_in, const int* in_sizes, int n_in,
                              void* d_out, int out_size, void* d_ws, size_t ws_size,
                              hipStream_t stream) {
    const float* X         = (const float*)d_in[0];
    const float* emb_ty    = (const float*)d_in[1];
    const float* W         = (const float*)d_in[2];
    const float* bias      = (const float*)d_in[3];
    const float* scale_log = (const float*)d_in[4];
    const float* eps       = (const float*)d_in[5];
    const int*   vertex    = (const int*)d_in[6];
    const int*   edges     = (const int*)d_in[7];
    const int*   type_ids  = (const int*)d_in[8];

    const int N   = in_sizes[0] / 128;   // 100000
    const int nnz = in_sizes[6];         // 1000000

    float* Xh = (float*)d_ws;                         // N*128 floats (51.2 MB)
    float* Xe = Xh + (size_t)N * 128;                 // E*128 floats (10.24 MB)

    // Zero the edge-segment accumulator (ws is poisoned 0xAA each call).
    hipMemsetAsync(Xe, 0, (size_t)E_SEGS * 128 * sizeof(float), stream);

    float* out = (float*)d_out;

    // 1) Xh = lorentz(X W^T + b); also out = Xh
    lorentz_gemm_kernel<<<(N + 63) / 64, 256, 0, stream>>>(
        X, W, bias, scale_log, Xh, out, N);

    // 2) Xe[s] += Xh[vertex] - emb[ty]
    int blocks_e = (int)(((size_t)nnz * 32 + 255) / 256);
    edge_scatter_kernel<<<blocks_e, 256, 0, stream>>>(
        Xh, emb_ty, vertex, edges, type_ids, Xe, nnz);

    // 3) out[v] += eps * Xe[s]   (out already holds Xh)
    vertex_scatter_kernel<<<blocks_e, 256, 0, stream>>>(
        Xe, vertex, edges, eps, out, nnz);
}

// Round 5
// 717.469 us; speedup vs baseline: 5.0355x; 5.0355x over previous
//
#include <hip/hip_runtime.h>
#include <hip/hip_bf16.h>

// H2Conv: Xh = lorentz_linear(X W^T + b); Xve = Xh[vertex]-emb[ty];
// Xe = segsum(Xve, edges); Xv = segsum(Xe[edges], vertex); out = eps*Xv + Xh
// N=100000, E=20000, NNZ=1e6, D=128. vertex < 2^17, type < 16.
//
// R1-R4: fp32-atomic scatters (2 GB WRITE_SIZE each, ~3.3 ms of the 3.6 ms
// baseline) replaced by on-device CSR build + pure gather kernels.
// R4: identical resubmission of R3 (three acquisition timeouts, no data).

#define E_SEGS 20000

// ---------------- Kernel 1: fused GEMM + lorentz epilogue -------------------
// Block = 256 threads, 64 rows/block. LDS ~100KB. Thread tile 4x8.
__global__ __launch_bounds__(256) void lorentz_gemm_kernel(
    const float* __restrict__ X, const float* __restrict__ W,
    const float* __restrict__ bias, const float* __restrict__ scale_log,
    float* __restrict__ Xh, int N)
{
    __shared__ float Wt[128][132];   // Wt[k][d]
    __shared__ float Xs[128][64];    // Xs[k][r]
    const int t = threadIdx.x;

    #pragma unroll
    for (int i = 0; i < 16; ++i) {
        int f4 = t + i * 256;
        int d  = f4 >> 5;
        int k0 = (f4 & 31) << 2;
        float4 w = ((const float4*)W)[f4];
        Wt[k0+0][d] = w.x; Wt[k0+1][d] = w.y;
        Wt[k0+2][d] = w.z; Wt[k0+3][d] = w.w;
    }
    const int row0 = blockIdx.x * 64;
    #pragma unroll
    for (int i = 0; i < 8; ++i) {
        int f4 = t + i * 256;
        int r  = f4 >> 5;
        int k0 = (f4 & 31) << 2;
        int gr = row0 + r;
        float4 x = make_float4(0.f, 0.f, 0.f, 0.f);
        if (gr < N) x = ((const float4*)X)[(size_t)gr * 32 + (f4 & 31)];
        Xs[k0+0][r] = x.x; Xs[k0+1][r] = x.y;
        Xs[k0+2][r] = x.z; Xs[k0+3][r] = x.w;
    }
    __syncthreads();

    const int rg = t >> 4;
    const int cg = t & 15;
    const int cb = cg << 3;

    float acc[4][8];
    #pragma unroll
    for (int r = 0; r < 4; ++r)
        #pragma unroll
        for (int j = 0; j < 8; ++j) acc[r][j] = 0.f;

    #pragma unroll 4
    for (int k = 0; k < 128; ++k) {
        float4 xr = *(const float4*)&Xs[k][rg << 2];
        float4 w0 = *(const float4*)&Wt[k][cb];
        float4 w1 = *(const float4*)&Wt[k][cb + 4];
        #pragma unroll
        for (int r = 0; r < 4; ++r) {
            float xv = (&xr.x)[r];
            acc[r][0] += xv * w0.x; acc[r][1] += xv * w0.y;
            acc[r][2] += xv * w0.z; acc[r][3] += xv * w0.w;
            acc[r][4] += xv * w1.x; acc[r][5] += xv * w1.y;
            acc[r][6] += xv * w1.z; acc[r][7] += xv * w1.w;
        }
    }

    float4 b0 = ((const float4*)bias)[cg * 2];
    float4 b1 = ((const float4*)bias)[cg * 2 + 1];
    #pragma unroll
    for (int r = 0; r < 4; ++r) {
        acc[r][0] += b0.x; acc[r][1] += b0.y; acc[r][2] += b0.z; acc[r][3] += b0.w;
        acc[r][4] += b1.x; acc[r][5] += b1.y; acc[r][6] += b1.z; acc[r][7] += b1.w;
    }

    const float es = expf(scale_log[0]);

    #pragma unroll
    for (int r = 0; r < 4; ++r) {
        float sq = 0.f;
        #pragma unroll
        for (int j = 0; j < 8; ++j) sq += acc[r][j] * acc[r][j];
        if (cg == 0) sq -= acc[r][0] * acc[r][0];
        #pragma unroll
        for (int m = 1; m < 16; m <<= 1) sq += __shfl_xor(sq, m, 16);
        float y0   = __shfl(acc[r][0], 0, 16);
        float time = es / (1.f + expf(-y0)) + 1.1f;
        float ss   = sqrtf((time * time - 1.f) / (sq + 1e-8f));
        float4 o0, o1;
        o0.x = (cg == 0) ? time : acc[r][0] * ss;
        o0.y = acc[r][1] * ss; o0.z = acc[r][2] * ss; o0.w = acc[r][3] * ss;
        o1.x = acc[r][4] * ss; o1.y = acc[r][5] * ss;
        o1.z = acc[r][6] * ss; o1.w = acc[r][7] * ss;
        int grow = row0 + (rg << 2) + r;
        if (grow < N) {
            float4* ph = (float4*)(Xh + (size_t)grow * 128 + cb);
            ph[0] = o0; ph[1] = o1;
        }
    }
}

// ---------------- CSR build -------------------------------------------------
// merged histogram: both edge- and vertex-keys in one pass
__global__ __launch_bounds__(256) void count_both_kernel(
    const int* __restrict__ edges, const int* __restrict__ vertex,
    int* __restrict__ hist_e, int* __restrict__ hist_v, int n)
{
    int i = blockIdx.x * 256 + threadIdx.x;
    if (i < n) {
        atomicAdd(&hist_e[edges[i]], 1);
        atomicAdd(&hist_v[vertex[i]], 1);
    }
}

// single-block exclusive scan, 4 elems/thread; offs has n+1 entries
__global__ __launch_bounds__(1024) void scan_kernel(
    const int* __restrict__ counts, int* __restrict__ offs, int n)
{
    __shared__ int buf[1024];
    __shared__ int s_carry;
    const int tid = threadIdx.x;
    if (tid == 0) s_carry = 0;
    __syncthreads();
    for (int base = 0; base < n; base += 4096) {
        int i0 = base + tid * 4;
        int c0 = (i0 + 0 < n) ? counts[i0 + 0] : 0;
        int c1 = (i0 + 1 < n) ? counts[i0 + 1] : 0;
        int c2 = (i0 + 2 < n) ? counts[i0 + 2] : 0;
        int c3 = (i0 + 3 < n) ? counts[i0 + 3] : 0;
        int s = c0 + c1 + c2 + c3;
        buf[tid] = s;
        __syncthreads();
        for (int off = 1; off < 1024; off <<= 1) {
            int t = (tid >= off) ? buf[tid - off] : 0;
            __syncthreads();
            buf[tid] += t;
            __syncthreads();
        }
        int incl  = buf[tid];
        int total = buf[1023];
        int carry = s_carry;
        int ex = carry + incl - s;
        if (i0 + 0 < n) offs[i0 + 0] = ex;
        if (i0 + 1 < n) offs[i0 + 1] = ex + c0;
        if (i0 + 2 < n) offs[i0 + 2] = ex + c0 + c1;
        if (i0 + 3 < n) offs[i0 + 3] = ex + c0 + c1 + c2;
        __syncthreads();
        if (tid == 0) s_carry = carry + total;
        __syncthreads();
    }
    if (tid == 0) offs[n] = s_carry;
}

// merged placement: edge-side payload = vertex|(type<<17); vertex-side = seg
__global__ __launch_bounds__(256) void fill_both_kernel(
    const int* __restrict__ edges, const int* __restrict__ vertex,
    const int* __restrict__ types,
    const int* __restrict__ offs_e, int* __restrict__ cur_e,
    int* __restrict__ vals_e,
    const int* __restrict__ offs_v, int* __restrict__ cur_v,
    int* __restrict__ segs_v, int n)
{
    int i = blockIdx.x * 256 + threadIdx.x;
    if (i < n) {
        int s = edges[i];
        int v = vertex[i];
        int pe = atomicAdd(&cur_e[s], 1);
        vals_e[offs_e[s] + pe] = v | (types[i] << 17);
        int pv = atomicAdd(&cur_v[v], 1);
        segs_v[offs_v[v] + pv] = s;
    }
}

// ---------------- Kernel 2: Xe[s] = sum_e (Xh[vertex[e]] - emb[ty[e]]) ------
// 1 wave per segment; lane owns a float2 of the 128-float row.
__global__ __launch_bounds__(256) void edge_gather_kernel(
    const float* __restrict__ Xh, const float* __restrict__ emb,
    const int* __restrict__ offs, const int* __restrict__ vals,
    float* __restrict__ Xe, int nsegs)
{
    int seg = blockIdx.x * 4 + (threadIdx.x >> 6);
    if (seg >= nsegs) return;
    int lane = threadIdx.x & 63;
    int beg = offs[seg], end = offs[seg + 1];
    float2 acc = make_float2(0.f, 0.f);
    int e = beg;
    for (; e + 1 < end; e += 2) {
        int p0 = vals[e], p1 = vals[e + 1];
        int v0 = p0 & 0x1FFFF, t0 = p0 >> 17;
        int v1 = p1 & 0x1FFFF, t1 = p1 >> 17;
        float2 a  = ((const float2*)Xh)[(size_t)v0 * 64 + lane];
        float2 b  = ((const float2*)Xh)[(size_t)v1 * 64 + lane];
        float2 m0 = ((const float2*)emb)[t0 * 64 + lane];
        float2 m1 = ((const float2*)emb)[t1 * 64 + lane];
        acc.x += (a.x - m0.x) + (b.x - m1.x);
        acc.y += (a.y - m0.y) + (b.y - m1.y);
    }
    if (e < end) {
        int p0 = vals[e];
        int v0 = p0 & 0x1FFFF, t0 = p0 >> 17;
        float2 a  = ((const float2*)Xh)[(size_t)v0 * 64 + lane];
        float2 m0 = ((const float2*)emb)[t0 * 64 + lane];
        acc.x += a.x - m0.x;
        acc.y += a.y - m0.y;
    }
    ((float2*)Xe)[(size_t)seg * 64 + lane] = acc;
}

// ---------------- Kernel 3: out[v] = Xh[v] + eps * sum_e Xe[seg[e]] ---------
__global__ __launch_bounds__(256) void vertex_gather_kernel(
    const float* __restrict__ Xh, const float* __restrict__ Xe,
    const int* __restrict__ offs, const int* __restrict__ segs,
    const float* __restrict__ eps, float* __restrict__ out, int N)
{
    int v = blockIdx.x * 4 + (threadIdx.x >> 6);
    if (v >= N) return;
    int lane = threadIdx.x & 63;
    int beg = offs[v], end = offs[v + 1];
    float2 acc = make_float2(0.f, 0.f);
    int e = beg;
    for (; e + 1 < end; e += 2) {
        int s0 = segs[e], s1 = segs[e + 1];
        float2 a = ((const float2*)Xe)[(size_t)s0 * 64 + lane];
        float2 b = ((const float2*)Xe)[(size_t)s1 * 64 + lane];
        acc.x += a.x + b.x;
        acc.y += a.y + b.y;
    }
    if (e < end) {
        int s0 = segs[e];
        float2 a = ((const float2*)Xe)[(size_t)s0 * 64 + lane];
        acc.x += a.x;
        acc.y += a.y;
    }
    float ep = eps[0];
    float2 xh = ((const float2*)Xh)[(size_t)v * 64 + lane];
    float2 o;
    o.x = xh.x + ep * acc.x;
    o.y = xh.y + ep * acc.y;
    ((float2*)out)[(size_t)v * 64 + lane] = o;
}

extern "C" void kernel_launch(void* const* d_in, const int* in_sizes, int n_in,
                              void* d_out, int out_size, void* d_ws, size_t ws_size,
                              hipStream_t stream) {
    const float* X         = (const float*)d_in[0];
    const float* emb_ty    = (const float*)d_in[1];
    const float* W         = (const float*)d_in[2];
    const float* bias      = (const float*)d_in[3];
    const float* scale_log = (const float*)d_in[4];
    const float* eps       = (const float*)d_in[5];
    const int*   vertex    = (const int*)d_in[6];
    const int*   edges     = (const int*)d_in[7];
    const int*   type_ids  = (const int*)d_in[8];

    const int N   = in_sizes[0] / 128;   // 100000
    const int nnz = in_sizes[6];         // 1000000
    const int E   = E_SEGS;              // 20000

    // ---- workspace layout (~71 MB total) ----
    float* Xh = (float*)d_ws;                       // N*128 floats (51.2 MB)
    float* Xe = Xh + (size_t)N * 128;               // E*128 floats (10.24 MB)
    int* ip      = (int*)(Xe + (size_t)E * 128);
    int* offs_e  = ip;              ip += E + 1;    // 20001
    int* offs_v  = ip;              ip += N + 1;    // 100001
    int* hist_e  = ip;              ip += E;        // \ contiguous zero region
    int* hist_v  = ip;              ip += N;        // |
    int* cur_e   = ip;              ip += E;        // |
    int* cur_v   = ip;              ip += N;        // / (2E+2N ints)
    int* vals_e  = ip;              ip += nnz;      // 1M: vertex|type<<17
    int* segs_v  = ip;              ip += nnz;      // 1M: segment id

    // zero hist+cursor region in one memset
    hipMemsetAsync(hist_e, 0, (size_t)(2 * E + 2 * N) * sizeof(int), stream);

    float* out = (float*)d_out;
    int blocks_nnz = (nnz + 255) / 256;

    // 1) CSR builds (independent of GEMM; keeps Xh hot for gathers)
    count_both_kernel<<<blocks_nnz, 256, 0, stream>>>(
        edges, vertex, hist_e, hist_v, nnz);
    scan_kernel<<<1, 1024, 0, stream>>>(hist_e, offs_e, E);
    scan_kernel<<<1, 1024, 0, stream>>>(hist_v, offs_v, N);
    fill_both_kernel<<<blocks_nnz, 256, 0, stream>>>(
        edges, vertex, type_ids, offs_e, cur_e, vals_e, offs_v, cur_v,
        segs_v, nnz);

    // 2) Xh = lorentz(X W^T + b)
    lorentz_gemm_kernel<<<(N + 63) / 64, 256, 0, stream>>>(
        X, W, bias, scale_log, Xh, N);

    // 3) Xe = segsum(Xh[vertex]-emb[ty]) over edge segments (no atomics)
    edge_gather_kernel<<<(E + 3) / 4, 256, 0, stream>>>(
        Xh, emb_ty, offs_e, vals_e, Xe, E);

    // 4) out = Xh + eps * segsum(Xe[edges]) over vertices (no atomics)
    vertex_gather_kernel<<<(N + 3) / 4, 256, 0, stream>>>(
        Xh, Xe, offs_v, segs_v, eps, out, N);
}

// Round 6
// 574.579 us; speedup vs baseline: 6.2877x; 1.2487x over previous
//
#include <hip/hip_runtime.h>
#include <hip/hip_bf16.h>

// H2Conv: Xh = lorentz_linear(X W^T + b); Xve = Xh[vertex]-emb[ty];
// Xe = segsum(Xve, edges); Xv = segsum(Xe[edges], vertex); out = eps*Xv + Xh
// N=100000, E=20000, NNZ=1e6, D=128. vertex < 2^17, type < 16.
//
// R5: (a) GEMM LDS layout rebuilt natural-row-major + XOR swizzle
//     (SQ_LDS_BANK_CONFLICT was 5.5e7 = ~90us of serialization);
//     (b) single-block scans -> 3-phase hierarchical scan;
//     (c) gathers float4/lane, 2 rows in flight per wave.

#define E_SEGS 20000

// ---------------- Kernel 1: fused GEMM + lorentz epilogue -------------------
// 64 rows/block, 256 threads. LDS: Ws[128][32]f4 swizzled (64KB) +
// Xs[64][33]f4 (33.8KB). Thread tile 4x8, dot4 inner loop.
__global__ __launch_bounds__(256) void lorentz_gemm_kernel(
    const float* __restrict__ X, const float* __restrict__ W,
    const float* __restrict__ bias, const float* __restrict__ scale_log,
    float* __restrict__ Xh, int N)
{
    __shared__ float4 Ws[128 * 32];  // (d, k4) at d*32 + (k4 ^ ((d>>3)&7))
    __shared__ float4 Xs[64 * 33];   // (r, k4) at r*33 + k4 (pad row: 33 f4)
    const int t = threadIdx.x;

    // Stage W natural layout: consecutive lanes -> consecutive c -> XOR-const
    // permutation of 32 consecutive f4 slots => conflict-free writes.
    #pragma unroll
    for (int i = 0; i < 16; ++i) {
        int f4 = t + i * 256;            // 0..4095
        int d  = f4 >> 5;                // 0..127
        int c  = f4 & 31;                // k4
        Ws[d * 32 + (c ^ ((d >> 3) & 7))] = ((const float4*)W)[f4];
    }
    // Stage X tile natural layout (conflict-free writes).
    const int row0 = blockIdx.x * 64;
    #pragma unroll
    for (int i = 0; i < 8; ++i) {
        int f4 = t + i * 256;            // 0..2047
        int r  = f4 >> 5;
        int c  = f4 & 31;
        int gr = row0 + r;
        float4 x = make_float4(0.f, 0.f, 0.f, 0.f);
        if (gr < N) x = ((const float4*)X)[(size_t)gr * 32 + c];
        Xs[r * 33 + c] = x;
    }
    __syncthreads();

    const int rg  = t >> 4;              // 0..15 -> rows rg*4..+3
    const int cg  = t & 15;              // 0..15 -> cols cg*8..+7
    const int r0  = rg << 2;
    const int swz = cg & 7;

    float acc[4][8];
    #pragma unroll
    for (int r = 0; r < 4; ++r)
        #pragma unroll
        for (int j = 0; j < 8; ++j) acc[r][j] = 0.f;

    // Reads: Xs broadcast 16-way, 2 bank-groups x2 (free); Ws: kk^ (cg&7)
    // spreads the 16 cg rows over all 8 bank-groups -> 2-way (free).
    #pragma unroll 2
    for (int k4 = 0; k4 < 32; ++k4) {
        float4 xq[4];
        #pragma unroll
        for (int rr = 0; rr < 4; ++rr) xq[rr] = Xs[(r0 + rr) * 33 + k4];
        float4 wq[8];
        const int kk = k4 ^ swz;
        #pragma unroll
        for (int j = 0; j < 8; ++j) wq[j] = Ws[(cg * 8 + j) * 32 + kk];
        #pragma unroll
        for (int rr = 0; rr < 4; ++rr)
            #pragma unroll
            for (int j = 0; j < 8; ++j)
                acc[rr][j] += xq[rr].x * wq[j].x + xq[rr].y * wq[j].y
                            + xq[rr].z * wq[j].z + xq[rr].w * wq[j].w;
    }

    const int cb = cg << 3;
    float4 b0 = ((const float4*)bias)[cg * 2];
    float4 b1 = ((const float4*)bias)[cg * 2 + 1];
    #pragma unroll
    for (int r = 0; r < 4; ++r) {
        acc[r][0] += b0.x; acc[r][1] += b0.y; acc[r][2] += b0.z; acc[r][3] += b0.w;
        acc[r][4] += b1.x; acc[r][5] += b1.y; acc[r][6] += b1.z; acc[r][7] += b1.w;
    }

    const float es = expf(scale_log[0]);

    #pragma unroll
    for (int r = 0; r < 4; ++r) {
        float sq = 0.f;
        #pragma unroll
        for (int j = 0; j < 8; ++j) sq += acc[r][j] * acc[r][j];
        if (cg == 0) sq -= acc[r][0] * acc[r][0];   // exclude time channel
        #pragma unroll
        for (int m = 1; m < 16; m <<= 1) sq += __shfl_xor(sq, m, 16);
        float y0   = __shfl(acc[r][0], 0, 16);
        float time = es / (1.f + expf(-y0)) + 1.1f;
        float ss   = sqrtf((time * time - 1.f) / (sq + 1e-8f));
        float4 o0, o1;
        o0.x = (cg == 0) ? time : acc[r][0] * ss;
        o0.y = acc[r][1] * ss; o0.z = acc[r][2] * ss; o0.w = acc[r][3] * ss;
        o1.x = acc[r][4] * ss; o1.y = acc[r][5] * ss;
        o1.z = acc[r][6] * ss; o1.w = acc[r][7] * ss;
        int grow = row0 + r0 + r;
        if (grow < N) {
            float4* ph = (float4*)(Xh + (size_t)grow * 128 + cb);
            ph[0] = o0; ph[1] = o1;
        }
    }
}

// ---------------- CSR build -------------------------------------------------
__global__ __launch_bounds__(256) void count_both_kernel(
    const int* __restrict__ edges, const int* __restrict__ vertex,
    int* __restrict__ hist_e, int* __restrict__ hist_v, int n)
{
    int i = blockIdx.x * 256 + threadIdx.x;
    if (i < n) {
        atomicAdd(&hist_e[edges[i]], 1);
        atomicAdd(&hist_v[vertex[i]], 1);
    }
}

// --- hierarchical exclusive scan: A) per-block (1024 elems), B) block sums,
//     C) add-back + write offs[n]=total ---
__global__ __launch_bounds__(256) void scan_partial_kernel(
    const int* __restrict__ counts, int* __restrict__ offs,
    int* __restrict__ bsums, int n)
{
    __shared__ int buf[256];
    const int b = blockIdx.x, tid = threadIdx.x;
    const int i0 = b * 1024 + tid * 4;
    int c0 = (i0 + 0 < n) ? counts[i0 + 0] : 0;
    int c1 = (i0 + 1 < n) ? counts[i0 + 1] : 0;
    int c2 = (i0 + 2 < n) ? counts[i0 + 2] : 0;
    int c3 = (i0 + 3 < n) ? counts[i0 + 3] : 0;
    int s = c0 + c1 + c2 + c3;
    buf[tid] = s;
    __syncthreads();
    #pragma unroll
    for (int off = 1; off < 256; off <<= 1) {
        int v = (tid >= off) ? buf[tid - off] : 0;
        __syncthreads();
        buf[tid] += v;
        __syncthreads();
    }
    int ex = buf[tid] - s;
    if (i0 + 0 < n) offs[i0 + 0] = ex;
    if (i0 + 1 < n) offs[i0 + 1] = ex + c0;
    if (i0 + 2 < n) offs[i0 + 2] = ex + c0 + c1;
    if (i0 + 3 < n) offs[i0 + 3] = ex + c0 + c1 + c2;
    if (tid == 255) bsums[b] = buf[255];
}

__global__ __launch_bounds__(256) void scan_bsums_kernel(
    int* __restrict__ bsums, int nb)   // nb <= 256
{
    __shared__ int buf[256];
    const int tid = threadIdx.x;
    int v = (tid < nb) ? bsums[tid] : 0;
    buf[tid] = v;
    __syncthreads();
    #pragma unroll
    for (int off = 1; off < 256; off <<= 1) {
        int u = (tid >= off) ? buf[tid - off] : 0;
        __syncthreads();
        buf[tid] += u;
        __syncthreads();
    }
    if (tid < nb) bsums[tid] = buf[tid] - v;   // exclusive
}

__global__ __launch_bounds__(256) void scan_add_kernel(
    int* __restrict__ offs, const int* __restrict__ bsums, int n, int total)
{
    const int b = blockIdx.x, tid = threadIdx.x;
    const int add = bsums[b];
    const int i0 = b * 1024 + tid * 4;
    if (add != 0) {
        if (i0 + 0 < n) offs[i0 + 0] += add;
        if (i0 + 1 < n) offs[i0 + 1] += add;
        if (i0 + 2 < n) offs[i0 + 2] += add;
        if (i0 + 3 < n) offs[i0 + 3] += add;
    }
    if (b == 0 && tid == 0) offs[n] = total;   // sum of counts == nnz
}

// merged placement: edge-side payload = vertex|(type<<17); vertex-side = seg
__global__ __launch_bounds__(256) void fill_both_kernel(
    const int* __restrict__ edges, const int* __restrict__ vertex,
    const int* __restrict__ types,
    const int* __restrict__ offs_e, int* __restrict__ cur_e,
    int* __restrict__ vals_e,
    const int* __restrict__ offs_v, int* __restrict__ cur_v,
    int* __restrict__ segs_v, int n)
{
    int i = blockIdx.x * 256 + threadIdx.x;
    if (i < n) {
        int s = edges[i];
        int v = vertex[i];
        int pe = atomicAdd(&cur_e[s], 1);
        vals_e[offs_e[s] + pe] = v | (types[i] << 17);
        int pv = atomicAdd(&cur_v[v], 1);
        segs_v[offs_v[v] + pv] = s;
    }
}

// ---------------- Kernel 2: Xe[s] = sum_e (Xh[vertex[e]] - emb[ty[e]]) ------
// 1 wave/segment; half-wave owns one row (32 lanes x float4), 2 edges/iter.
__global__ __launch_bounds__(256) void edge_gather_kernel(
    const float* __restrict__ Xh, const float* __restrict__ emb,
    const int* __restrict__ offs, const int* __restrict__ vals,
    float* __restrict__ Xe, int nsegs)
{
    int seg = blockIdx.x * 4 + (threadIdx.x >> 6);
    if (seg >= nsegs) return;
    const int lane = threadIdx.x & 63;
    const int h = lane >> 5, l5 = lane & 31;
    const int beg = offs[seg], end = offs[seg + 1];
    float4 acc = make_float4(0.f, 0.f, 0.f, 0.f);
    for (int e = beg + h; e < end; e += 2) {
        int p  = vals[e];
        int v  = p & 0x1FFFF, ty = p >> 17;
        float4 a = ((const float4*)Xh)[(size_t)v * 32 + l5];
        float4 m = ((const float4*)emb)[ty * 32 + l5];
        acc.x += a.x - m.x; acc.y += a.y - m.y;
        acc.z += a.z - m.z; acc.w += a.w - m.w;
    }
    acc.x += __shfl_xor(acc.x, 32);
    acc.y += __shfl_xor(acc.y, 32);
    acc.z += __shfl_xor(acc.z, 32);
    acc.w += __shfl_xor(acc.w, 32);
    if (h == 0) ((float4*)Xe)[(size_t)seg * 32 + l5] = acc;
}

// ---------------- Kernel 3: out[v] = Xh[v] + eps * sum_e Xe[seg[e]] ---------
__global__ __launch_bounds__(256) void vertex_gather_kernel(
    const float* __restrict__ Xh, const float* __restrict__ Xe,
    const int* __restrict__ offs, const int* __restrict__ segs,
    const float* __restrict__ eps, float* __restrict__ out, int N)
{
    int v = blockIdx.x * 4 + (threadIdx.x >> 6);
    if (v >= N) return;
    const int lane = threadIdx.x & 63;
    const int h = lane >> 5, l5 = lane & 31;
    const int beg = offs[v], end = offs[v + 1];
    float4 acc = make_float4(0.f, 0.f, 0.f, 0.f);
    for (int e = beg + h; e < end; e += 2) {
        int s = segs[e];
        float4 a = ((const float4*)Xe)[(size_t)s * 32 + l5];
        acc.x += a.x; acc.y += a.y; acc.z += a.z; acc.w += a.w;
    }
    acc.x += __shfl_xor(acc.x, 32);
    acc.y += __shfl_xor(acc.y, 32);
    acc.z += __shfl_xor(acc.z, 32);
    acc.w += __shfl_xor(acc.w, 32);
    if (h == 0) {
        float ep = eps[0];
        float4 xh = ((const float4*)Xh)[(size_t)v * 32 + l5];
        float4 o;
        o.x = xh.x + ep * acc.x; o.y = xh.y + ep * acc.y;
        o.z = xh.z + ep * acc.z; o.w = xh.w + ep * acc.w;
        ((float4*)out)[(size_t)v * 32 + l5] = o;
    }
}

extern "C" void kernel_launch(void* const* d_in, const int* in_sizes, int n_in,
                              void* d_out, int out_size, void* d_ws, size_t ws_size,
                              hipStream_t stream) {
    const float* X         = (const float*)d_in[0];
    const float* emb_ty    = (const float*)d_in[1];
    const float* W         = (const float*)d_in[2];
    const float* bias      = (const float*)d_in[3];
    const float* scale_log = (const float*)d_in[4];
    const float* eps       = (const float*)d_in[5];
    const int*   vertex    = (const int*)d_in[6];
    const int*   edges     = (const int*)d_in[7];
    const int*   type_ids  = (const int*)d_in[8];

    const int N   = in_sizes[0] / 128;   // 100000
    const int nnz = in_sizes[6];         // 1000000
    const int E   = E_SEGS;              // 20000

    // ---- workspace layout (~71 MB total) ----
    float* Xh = (float*)d_ws;                       // N*128 floats (51.2 MB)
    float* Xe = Xh + (size_t)N * 128;               // E*128 floats (10.24 MB)
    int* ip      = (int*)(Xe + (size_t)E * 128);
    int* offs_e  = ip;              ip += E + 1;    // 20001
    int* offs_v  = ip;              ip += N + 1;    // 100001
    int* hist_e  = ip;              ip += E;        // \ contiguous zero region
    int* hist_v  = ip;              ip += N;        // |
    int* cur_e   = ip;              ip += E;        // |
    int* cur_v   = ip;              ip += N;        // / (2E+2N ints)
    int* bsum_e  = ip;              ip += 256;
    int* bsum_v  = ip;              ip += 256;
    int* vals_e  = ip;              ip += nnz;      // 1M: vertex|type<<17
    int* segs_v  = ip;              ip += nnz;      // 1M: segment id

    hipMemsetAsync(hist_e, 0, (size_t)(2 * E + 2 * N) * sizeof(int), stream);

    float* out = (float*)d_out;
    const int blocks_nnz = (nnz + 255) / 256;
    const int nb_e = (E + 1023) / 1024;   // 20
    const int nb_v = (N + 1023) / 1024;   // 98

    // 1) histograms
    count_both_kernel<<<blocks_nnz, 256, 0, stream>>>(
        edges, vertex, hist_e, hist_v, nnz);

    // 2) hierarchical exclusive scans
    scan_partial_kernel<<<nb_e, 256, 0, stream>>>(hist_e, offs_e, bsum_e, E);
    scan_partial_kernel<<<nb_v, 256, 0, stream>>>(hist_v, offs_v, bsum_v, N);
    scan_bsums_kernel<<<1, 256, 0, stream>>>(bsum_e, nb_e);
    scan_bsums_kernel<<<1, 256, 0, stream>>>(bsum_v, nb_v);
    scan_add_kernel<<<nb_e, 256, 0, stream>>>(offs_e, bsum_e, E, nnz);
    scan_add_kernel<<<nb_v, 256, 0, stream>>>(offs_v, bsum_v, N, nnz);

    // 3) CSR placement
    fill_both_kernel<<<blocks_nnz, 256, 0, stream>>>(
        edges, vertex, type_ids, offs_e, cur_e, vals_e, offs_v, cur_v,
        segs_v, nnz);

    // 4) Xh = lorentz(X W^T + b)
    lorentz_gemm_kernel<<<(N + 63) / 64, 256, 0, stream>>>(
        X, W, bias, scale_log, Xh, N);

    // 5) Xe = segsum(Xh[vertex]-emb[ty]) over edge segments
    edge_gather_kernel<<<(E + 3) / 4, 256, 0, stream>>>(
        Xh, emb_ty, offs_e, vals_e, Xe, E);

    // 6) out = Xh + eps * segsum(Xe[edges]) over vertices
    vertex_gather_kernel<<<(N + 3) / 4, 256, 0, stream>>>(
        Xh, Xe, offs_v, segs_v, eps, out, N);
}